// Round 1
// baseline (265.369 us; speedup 1.0000x reference)
//
#include <hip/hip_runtime.h>
#include <math.h>

#define NUM_EMB 512
#define EMB_DIM 64
#define S_SPATIAL 32768   // 32*32*32
#define BATCH 4
#define NVEC (BATCH * S_SPATIAL)  // 131072 vectors

// Workspace layout (d_ws):
//   offset 0:    double loss_accum
//   offset 256:  float  cbnorm[NUM_EMB]

// ---------------------------------------------------------------------------
// Prep: cbnorm[k] = sum_c cb[k][c]^2  (separate mul+add rounding, mimicking
// jnp.sum(codebook*codebook, axis=1)); thread k==0 zeroes the loss accumulator.
// ---------------------------------------------------------------------------
__global__ void vq_prep(const float* __restrict__ cb,
                        float* __restrict__ cbnorm,
                        double* __restrict__ loss_accum) {
    int k = blockIdx.x * blockDim.x + threadIdx.x;
    if (k == 0) *loss_accum = 0.0;
    if (k < NUM_EMB) {
        const float* e = cb + k * EMB_DIM;
        float s = 0.f;
        #pragma unroll
        for (int c = 0; c < EMB_DIM; ++c)
            s = __fadd_rn(s, __fmul_rn(e[c], e[c]));
        cbnorm[k] = s;
    }
}

// ---------------------------------------------------------------------------
// Main: one thread per spatial vector. x[64] held in VGPRs; codebook accessed
// with wave-uniform addresses (k is a loop index) -> scalar loads (SGPRs),
// inner loop is pure v_fma_f32 with one SGPR operand.
// Distance mimics JAX rounding: d = fl(fl(xnorm + cbnorm[k]) - fl(2*dot)).
// First-index tie-break via strict '<', matching jnp.argmin.
// ---------------------------------------------------------------------------
__global__ __launch_bounds__(256) void vq_main(
        const float* __restrict__ in,
        const float* __restrict__ cb,
        const float* __restrict__ cbnorm,
        float* __restrict__ outq,          // d_out + 1 (quantized, [B,C,D,H,W])
        double* __restrict__ loss_accum) {
    const int n = blockIdx.x * 256 + threadIdx.x;   // vector id, < NVEC exactly
    const int b = n / S_SPATIAL;
    const int s = n % S_SPATIAL;

    const float* xp = in + (size_t)b * EMB_DIM * S_SPATIAL + s;
    float x[EMB_DIM];
    #pragma unroll
    for (int c = 0; c < EMB_DIM; ++c)
        x[c] = xp[(size_t)c * S_SPATIAL];           // coalesced across threads

    float xnorm = 0.f;
    #pragma unroll
    for (int c = 0; c < EMB_DIM; ++c)
        xnorm = __fadd_rn(xnorm, __fmul_rn(x[c], x[c]));

    float best = INFINITY;
    int bestk = 0;
    for (int k = 0; k < NUM_EMB; ++k) {
        const float* e = cb + k * EMB_DIM;          // wave-uniform -> s_load
        float a0 = 0.f, a1 = 0.f, a2 = 0.f, a3 = 0.f;
        #pragma unroll
        for (int c = 0; c < EMB_DIM; c += 4) {
            a0 = fmaf(x[c + 0], e[c + 0], a0);
            a1 = fmaf(x[c + 1], e[c + 1], a1);
            a2 = fmaf(x[c + 2], e[c + 2], a2);
            a3 = fmaf(x[c + 3], e[c + 3], a3);
        }
        float dot = __fadd_rn(__fadd_rn(a0, a1), __fadd_rn(a2, a3));
        float d = __fsub_rn(__fadd_rn(xnorm, cbnorm[k]),
                            __fmul_rn(2.f, dot));
        if (d < best) { best = d; bestk = k; }
    }

    // Gather winning code, write output (coalesced across threads), loss part.
    const float* q = cb + (size_t)bestk * EMB_DIM;  // per-lane gather, L2-hot
    float* op = outq + (size_t)b * EMB_DIM * S_SPATIAL + s;
    float lsum = 0.f;
    #pragma unroll
    for (int c = 0; c < EMB_DIM; ++c) {
        float qc = q[c];
        op[(size_t)c * S_SPATIAL] = qc;
        float diff = __fsub_rn(qc, x[c]);
        lsum = __fadd_rn(lsum, __fmul_rn(diff, diff));
    }

    // Block reduction of lsum -> one double atomicAdd per block.
    #pragma unroll
    for (int off = 32; off > 0; off >>= 1)
        lsum += __shfl_down(lsum, off, 64);
    __shared__ float wsum[4];
    const int lane = threadIdx.x & 63;
    const int wid  = threadIdx.x >> 6;
    if (lane == 0) wsum[wid] = lsum;
    __syncthreads();
    if (threadIdx.x == 0) {
        double t = ((double)wsum[0] + (double)wsum[1])
                 + ((double)wsum[2] + (double)wsum[3]);
        atomicAdd(loss_accum, t);
    }
}

// ---------------------------------------------------------------------------
// Finalize: loss = m + 0.25*m with m = mean((q - x)^2)
// ---------------------------------------------------------------------------
__global__ void vq_final(const double* __restrict__ loss_accum,
                         float* __restrict__ out0) {
    double m = *loss_accum / (double)((long long)NVEC * EMB_DIM);
    float mf = (float)m;
    out0[0] = __fadd_rn(mf, __fmul_rn(0.25f, mf));
}

extern "C" void kernel_launch(void* const* d_in, const int* in_sizes, int n_in,
                              void* d_out, int out_size, void* d_ws, size_t ws_size,
                              hipStream_t stream) {
    const float* in = (const float*)d_in[0];   // [4, 64, 32, 32, 32]
    const float* cb = (const float*)d_in[1];   // [512, 64]
    float* out = (float*)d_out;                // [0]=loss, [1..]=quantized

    double* loss_accum = (double*)d_ws;
    float* cbnorm = (float*)((char*)d_ws + 256);

    vq_prep<<<4, 128, 0, stream>>>(cb, cbnorm, loss_accum);
    vq_main<<<NVEC / 256, 256, 0, stream>>>(in, cb, cbnorm, out + 1, loss_accum);
    vq_final<<<1, 1, 0, stream>>>(loss_accum, out);
}

// Round 2
// 259.097 us; speedup vs baseline: 1.0242x; 1.0242x over previous
//
#include <hip/hip_runtime.h>
#include <math.h>

#define NUM_EMB 512
#define EMB_DIM 64
#define S_SPATIAL 32768   // 32*32*32
#define BATCH 4
#define NVEC (BATCH * S_SPATIAL)  // 131072 vectors

// Workspace layout (d_ws):
//   offset 0:    double loss_accum
//   offset 256:  float  cbnorm[NUM_EMB]

// ---------------------------------------------------------------------------
// Prep: cbnorm[k] = sum_c cb[k][c]^2 ; thread 0 zeroes the loss accumulator.
// ---------------------------------------------------------------------------
__global__ void vq_prep(const float* __restrict__ cb,
                        float* __restrict__ cbnorm,
                        double* __restrict__ loss_accum) {
    int k = blockIdx.x * blockDim.x + threadIdx.x;
    if (k == 0) *loss_accum = 0.0;
    if (k < NUM_EMB) {
        const float* e = cb + k * EMB_DIM;
        float s = 0.f;
        #pragma unroll
        for (int c = 0; c < EMB_DIM; ++c)
            s = __fadd_rn(s, __fmul_rn(e[c], e[c]));
        cbnorm[k] = s;
    }
}

// ---------------------------------------------------------------------------
// Main: one thread per spatial vector. x held in 16 NAMED float4 registers
// (no indexable array -> no scratch demotion; R1's VGPR=44 + 25MB scratch
// writes proved x[64] was spilled). Codebook row address is wave-uniform ->
// s_load into SGPRs; inner loop = 64 v_fma_f32 (VGPR x SGPR operands).
// FP order is bit-identical to the R1 passing version.
// ---------------------------------------------------------------------------
__global__ __launch_bounds__(256, 2) void vq_main(
        const float* __restrict__ in,
        const float* __restrict__ cb,
        const float* __restrict__ cbnorm,
        float* __restrict__ outq,          // d_out + 1 (quantized, [B,C,D,H,W])
        double* __restrict__ loss_accum) {
    const int n = blockIdx.x * 256 + threadIdx.x;   // vector id, < NVEC exactly
    const int b = n >> 15;          // n / S_SPATIAL
    const int s = n & (S_SPATIAL - 1);

    const float* xp = in + (size_t)b * EMB_DIM * S_SPATIAL + s;
    const size_t S = (size_t)S_SPATIAL;

    // ---- load x into 16 named float4 registers (coalesced across lanes) ----
#define LDX(i) const float4 x##i = make_float4(xp[(4*i+0)*S], xp[(4*i+1)*S], \
                                               xp[(4*i+2)*S], xp[(4*i+3)*S])
    LDX(0);  LDX(1);  LDX(2);  LDX(3);  LDX(4);  LDX(5);  LDX(6);  LDX(7);
    LDX(8);  LDX(9);  LDX(10); LDX(11); LDX(12); LDX(13); LDX(14); LDX(15);
#undef LDX

    // ---- xnorm, sequential c order (matches jnp.sum(flat*flat, axis=1)) ----
    float xn = 0.f;
#define XN(i) xn = __fadd_rn(xn, __fmul_rn(x##i.x, x##i.x)); \
              xn = __fadd_rn(xn, __fmul_rn(x##i.y, x##i.y)); \
              xn = __fadd_rn(xn, __fmul_rn(x##i.z, x##i.z)); \
              xn = __fadd_rn(xn, __fmul_rn(x##i.w, x##i.w))
    XN(0);  XN(1);  XN(2);  XN(3);  XN(4);  XN(5);  XN(6);  XN(7);
    XN(8);  XN(9);  XN(10); XN(11); XN(12); XN(13); XN(14); XN(15);
#undef XN

    // ---- argmin over 512 codes ----
    float best = INFINITY;
    int bestk = 0;
    for (int k = 0; k < NUM_EMB; ++k) {
        const float4* ev = (const float4*)(cb + (size_t)k * EMB_DIM); // uniform
        float a0 = 0.f, a1 = 0.f, a2 = 0.f, a3 = 0.f;
#define DOT(i) { const float4 e = ev[i];            \
                 a0 = fmaf(x##i.x, e.x, a0);        \
                 a1 = fmaf(x##i.y, e.y, a1);        \
                 a2 = fmaf(x##i.z, e.z, a2);        \
                 a3 = fmaf(x##i.w, e.w, a3); }
        DOT(0);  DOT(1);  DOT(2);  DOT(3);  DOT(4);  DOT(5);  DOT(6);  DOT(7);
        DOT(8);  DOT(9);  DOT(10); DOT(11); DOT(12); DOT(13); DOT(14); DOT(15);
#undef DOT
        float dot = __fadd_rn(__fadd_rn(a0, a1), __fadd_rn(a2, a3));
        float d = __fsub_rn(__fadd_rn(xn, cbnorm[k]),
                            __fmul_rn(2.f, dot));
        if (d < best) { best = d; bestk = k; }
    }

    // ---- gather winning code, write output, loss partial ----
    const float4* q = (const float4*)(cb + (size_t)bestk * EMB_DIM);
    float* op = outq + (size_t)b * EMB_DIM * S_SPATIAL + s;
    float lsum = 0.f;
#define OUTC(i) { const float4 qv = q[i];                                   \
                  op[(4*i+0)*S] = qv.x; op[(4*i+1)*S] = qv.y;               \
                  op[(4*i+2)*S] = qv.z; op[(4*i+3)*S] = qv.w;               \
                  float d0 = __fsub_rn(qv.x, x##i.x);                       \
                  float d1 = __fsub_rn(qv.y, x##i.y);                       \
                  float d2 = __fsub_rn(qv.z, x##i.z);                       \
                  float d3 = __fsub_rn(qv.w, x##i.w);                       \
                  lsum = __fadd_rn(lsum, __fmul_rn(d0, d0));                \
                  lsum = __fadd_rn(lsum, __fmul_rn(d1, d1));                \
                  lsum = __fadd_rn(lsum, __fmul_rn(d2, d2));                \
                  lsum = __fadd_rn(lsum, __fmul_rn(d3, d3)); }
    OUTC(0);  OUTC(1);  OUTC(2);  OUTC(3);  OUTC(4);  OUTC(5);  OUTC(6);  OUTC(7);
    OUTC(8);  OUTC(9);  OUTC(10); OUTC(11); OUTC(12); OUTC(13); OUTC(14); OUTC(15);
#undef OUTC

    // ---- block reduction of lsum -> one double atomicAdd per block ----
    #pragma unroll
    for (int off = 32; off > 0; off >>= 1)
        lsum += __shfl_down(lsum, off, 64);
    __shared__ float wsum[4];
    const int lane = threadIdx.x & 63;
    const int wid  = threadIdx.x >> 6;
    if (lane == 0) wsum[wid] = lsum;
    __syncthreads();
    if (threadIdx.x == 0) {
        double t = ((double)wsum[0] + (double)wsum[1])
                 + ((double)wsum[2] + (double)wsum[3]);
        atomicAdd(loss_accum, t);
    }
}

// ---------------------------------------------------------------------------
// Finalize: loss = m + 0.25*m with m = mean((q - x)^2)
// ---------------------------------------------------------------------------
__global__ void vq_final(const double* __restrict__ loss_accum,
                         float* __restrict__ out0) {
    double m = *loss_accum / (double)((long long)NVEC * EMB_DIM);
    float mf = (float)m;
    out0[0] = __fadd_rn(mf, __fmul_rn(0.25f, mf));
}

extern "C" void kernel_launch(void* const* d_in, const int* in_sizes, int n_in,
                              void* d_out, int out_size, void* d_ws, size_t ws_size,
                              hipStream_t stream) {
    const float* in = (const float*)d_in[0];   // [4, 64, 32, 32, 32]
    const float* cb = (const float*)d_in[1];   // [512, 64]
    float* out = (float*)d_out;                // [0]=loss, [1..]=quantized

    double* loss_accum = (double*)d_ws;
    float* cbnorm = (float*)((char*)d_ws + 256);

    vq_prep<<<4, 128, 0, stream>>>(cb, cbnorm, loss_accum);
    vq_main<<<NVEC / 256, 256, 0, stream>>>(in, cb, cbnorm, out + 1, loss_accum);
    vq_final<<<1, 1, 0, stream>>>(loss_accum, out);
}